// Round 1
// baseline (340.425 us; speedup 1.0000x reference)
//
#include <hip/hip_runtime.h>
#include <hip/hip_bf16.h>

#define B_ 8
#define N_ 4096
#define C_ 512
#define H_ 4
#define EPS_ 1e-4f
#define E60P 1.14200739e26f   // expf(60)
#define E60M 8.7565108e-27f   // expf(-60)

typedef __attribute__((ext_vector_type(8))) short short8;
typedef __attribute__((ext_vector_type(4))) float floatx4;
typedef unsigned short ushort_t;

__device__ __forceinline__ float sigmoidf_(float v) {
    return 1.0f / (1.0f + expf(-v));
}

// ---------------------------------------------------------------------------
// K1: per-subchunk (64 steps) partial sums  T[h] = sum A*x[t]*ep[t]
// grid: dir(2) x b(8) x ctile(8) x chunk(16) = 2048 blocks, 256 thr
// block: wave = subchunk-within-chunk (4), lane = channel-within-tile (64)
// ---------------------------------------------------------------------------
__global__ __launch_bounds__(256) void k_partials(
    const float* __restrict__ x, const float* __restrict__ al,
    const float* __restrict__ dl, const float* __restrict__ bl,
    float* __restrict__ P)
{
    int bid   = blockIdx.x;
    int chunk = bid & 15;
    int ct    = (bid >> 4) & 7;
    int b     = (bid >> 7) & 7;
    int dir   = bid >> 10;
    int lane  = threadIdx.x & 63;
    int wave  = threadIdx.x >> 6;
    int c     = ct * 64 + lane;
    int sub   = chunk * 4 + wave;   // 0..63
    int t0    = sub * 64;

    float aa[4], dd[4], bb[4];
    { float4 v = ((const float4*)al)[c]; aa[0]=v.x; aa[1]=v.y; aa[2]=v.z; aa[3]=v.w; }
    { float4 v = ((const float4*)dl)[c]; dd[0]=v.x; dd[1]=v.y; dd[2]=v.z; dd[3]=v.w; }
    { float4 v = ((const float4*)bl)[c]; bb[0]=v.x; bb[1]=v.y; bb[2]=v.z; bb[3]=v.w; }

    float A[H_], ri[H_], ep[H_], T[H_];
    #pragma unroll
    for (int h = 0; h < H_; ++h) {
        float alpha = sigmoidf_(aa[h]);
        float delta = sigmoidf_(dd[h]);
        float beta  = sigmoidf_(bb[h]);
        A[h] = alpha * beta;
        float r = fminf(fmaxf(1.0f - alpha * delta, EPS_), 1.0f - EPS_);
        float L = logf(r);
        ri[h] = 1.0f / r;
        ep[h] = expf(fminf(-L * (float)t0, 60.0f));
        T[h]  = 0.0f;
    }

    const float* xb = x + (b * N_) * C_ + c;
    int nbase = dir ? (N_ - 1 - t0) : t0;
    int nstep = dir ? -1 : 1;

    #pragma unroll 8
    for (int i = 0; i < 64; ++i) {
        float xv = xb[(nbase + i * nstep) * C_];
        #pragma unroll
        for (int h = 0; h < H_; ++h) {
            float ax = A[h] * xv;
            T[h]  = fmaf(ax, ep[h], T[h]);
            ep[h] = fminf(ep[h] * ri[h], E60P);
        }
    }

    float* pp = P + ((dir * 8 + b) * 64 + sub) * (H_ * C_) + c;
    #pragma unroll
    for (int h = 0; h < H_; ++h) pp[h * C_] = T[h];
}

// ---------------------------------------------------------------------------
// K2: in-place exclusive scan over the 64 subchunks, per (dir,b,c,h)
// grid: dir(2) x b(8) x ctile(8) = 128 blocks; thread = (h, c_local)
// ---------------------------------------------------------------------------
__global__ __launch_bounds__(256) void k_scan(float* __restrict__ P)
{
    int bid = blockIdx.x;
    int ct  = bid & 7;
    int b   = (bid >> 3) & 7;
    int dir = bid >> 6;
    int cl  = threadIdx.x & 63;
    int h   = threadIdx.x >> 6;
    int c   = ct * 64 + cl;

    float run = 0.0f;
    float* base = P + ((dir * 8 + b) * 64) * (H_ * C_) + h * C_ + c;
    for (int s = 0; s < 64; ++s) {
        float v = base[s * (H_ * C_)];
        base[s * (H_ * C_)] = run;
        run += v;
    }
}

// ---------------------------------------------------------------------------
// K3: re-scan with carry, produce z[b,n,dir*C+c] = sum_h eta*em*S  (bf16)
// same grid/decomposition as K1
// ---------------------------------------------------------------------------
__global__ __launch_bounds__(256) void k_apply(
    const float* __restrict__ x, const float* __restrict__ al,
    const float* __restrict__ dl, const float* __restrict__ bl,
    const float* __restrict__ eta, const float* __restrict__ P,
    __hip_bfloat16* __restrict__ z)
{
    int bid   = blockIdx.x;
    int chunk = bid & 15;
    int ct    = (bid >> 4) & 7;
    int b     = (bid >> 7) & 7;
    int dir   = bid >> 10;
    int lane  = threadIdx.x & 63;
    int wave  = threadIdx.x >> 6;
    int c     = ct * 64 + lane;
    int sub   = chunk * 4 + wave;
    int t0    = sub * 64;

    float aa[4], dd[4], bb[4], ee[4];
    { float4 v = ((const float4*)al )[c]; aa[0]=v.x; aa[1]=v.y; aa[2]=v.z; aa[3]=v.w; }
    { float4 v = ((const float4*)dl )[c]; dd[0]=v.x; dd[1]=v.y; dd[2]=v.z; dd[3]=v.w; }
    { float4 v = ((const float4*)bl )[c]; bb[0]=v.x; bb[1]=v.y; bb[2]=v.z; bb[3]=v.w; }
    { float4 v = ((const float4*)eta)[c]; ee[0]=v.x; ee[1]=v.y; ee[2]=v.z; ee[3]=v.w; }

    const float* cp = P + ((dir * 8 + b) * 64 + sub) * (H_ * C_) + c;

    float A[H_], rr[H_], ri[H_], ep[H_], em[H_], S[H_];
    #pragma unroll
    for (int h = 0; h < H_; ++h) {
        float alpha = sigmoidf_(aa[h]);
        float delta = sigmoidf_(dd[h]);
        float beta  = sigmoidf_(bb[h]);
        A[h] = alpha * beta;
        float r = fminf(fmaxf(1.0f - alpha * delta, EPS_), 1.0f - EPS_);
        float L = logf(r);
        rr[h] = r;
        ri[h] = 1.0f / r;
        ep[h] = expf(fminf(-L * (float)t0, 60.0f));
        em[h] = expf(fmaxf( L * (float)t0, -60.0f));
        S[h]  = cp[h * C_];    // carry-in (exclusive prefix)
    }

    const float* xb = x + (b * N_) * C_ + c;
    __hip_bfloat16* zb = z + (b * N_) * (2 * C_) + dir * C_ + c;
    int nbase = dir ? (N_ - 1 - t0) : t0;
    int nstep = dir ? -1 : 1;

    #pragma unroll 4
    for (int i = 0; i < 64; ++i) {
        int n = nbase + i * nstep;
        float xv = xb[n * C_];
        float y = 0.0f;
        #pragma unroll
        for (int h = 0; h < H_; ++h) {
            float ax = A[h] * xv;
            S[h]  = fmaf(ax, ep[h], S[h]);
            ep[h] = fminf(ep[h] * ri[h], E60P);
            y     = fmaf(ee[h], em[h] * S[h], y);
            em[h] = fmaxf(em[h] * rr[h], E60M);
        }
        zb[n * (2 * C_)] = __float2bfloat16(y);
    }
}

// ---------------------------------------------------------------------------
// cvt proj_w fp32 -> bf16
// ---------------------------------------------------------------------------
__global__ __launch_bounds__(256) void k_cvtw(const float* __restrict__ w,
                                              __hip_bfloat16* __restrict__ wb)
{
    int i = blockIdx.x * 256 + threadIdx.x;   // 524288 total
    wb[i] = __float2bfloat16(w[i]);
}

// ---------------------------------------------------------------------------
// K4: GEMM  out[M=32768, 512] = Z[M,1024] * W[512,1024]^T + bias
// bf16 MFMA 16x16x32, tiles BM=BN=128, BK=64, 4 waves in 2x2, 4x4 frags/wave
// ---------------------------------------------------------------------------
#define BM 128
#define BN 128
#define BK 64
#define LDK 72   // padded LDS leading dim (elements)

__global__ __launch_bounds__(256) void k_gemm(
    const ushort_t* __restrict__ Z, const ushort_t* __restrict__ W,
    const float* __restrict__ bias, float* __restrict__ out)
{
    __shared__ ushort_t sA[BM * LDK];
    __shared__ ushort_t sB[BN * LDK];

    int tid  = threadIdx.x;
    int m0   = blockIdx.x * BM;
    int n0   = blockIdx.y * BN;
    int lane = tid & 63, wave = tid >> 6;
    int wm   = wave & 1, wn = wave >> 1;
    int fr   = lane & 15, quad = lane >> 4;

    floatx4 acc[4][4];
    #pragma unroll
    for (int mf = 0; mf < 4; ++mf)
        #pragma unroll
        for (int nf = 0; nf < 4; ++nf)
            acc[mf][nf] = (floatx4){0.f, 0.f, 0.f, 0.f};

    for (int k0 = 0; k0 < 1024; k0 += BK) {
        uint4 va[4], vb[4];
        #pragma unroll
        for (int j = 0; j < 4; ++j) {
            int q   = tid + j * 256;
            int row = q >> 3, kg = q & 7;
            va[j] = *(const uint4*)(Z + (m0 + row) * 1024 + k0 + kg * 8);
            vb[j] = *(const uint4*)(W + (n0 + row) * 1024 + k0 + kg * 8);
        }
        __syncthreads();
        #pragma unroll
        for (int j = 0; j < 4; ++j) {
            int q   = tid + j * 256;
            int row = q >> 3, kg = q & 7;
            *(uint4*)&sA[row * LDK + kg * 8] = va[j];
            *(uint4*)&sB[row * LDK + kg * 8] = vb[j];
        }
        __syncthreads();

        short8 af[2][4], bf[2][4];
        #pragma unroll
        for (int ks = 0; ks < 2; ++ks)
            #pragma unroll
            for (int f = 0; f < 4; ++f) {
                af[ks][f] = *(const short8*)&sA[(wm * 64 + f * 16 + fr) * LDK + ks * 32 + quad * 8];
                bf[ks][f] = *(const short8*)&sB[(wn * 64 + f * 16 + fr) * LDK + ks * 32 + quad * 8];
            }

        #pragma unroll
        for (int ks = 0; ks < 2; ++ks)
            #pragma unroll
            for (int mf = 0; mf < 4; ++mf)
                #pragma unroll
                for (int nf = 0; nf < 4; ++nf)
                    acc[mf][nf] = __builtin_amdgcn_mfma_f32_16x16x32_bf16(
                        af[ks][mf], bf[ks][nf], acc[mf][nf], 0, 0, 0);
    }

    #pragma unroll
    for (int nf = 0; nf < 4; ++nf) {
        int n = n0 + wn * 64 + nf * 16 + fr;
        float bv = bias[n];
        #pragma unroll
        for (int mf = 0; mf < 4; ++mf) {
            #pragma unroll
            for (int rg = 0; rg < 4; ++rg) {
                int m = m0 + wm * 64 + mf * 16 + quad * 4 + rg;
                out[m * 512 + n] = acc[mf][nf][rg] + bv;
            }
        }
    }
}

// ---------------------------------------------------------------------------
extern "C" void kernel_launch(void* const* d_in, const int* in_sizes, int n_in,
                              void* d_out, int out_size, void* d_ws, size_t ws_size,
                              hipStream_t stream)
{
    const float* x  = (const float*)d_in[0];
    const float* al = (const float*)d_in[1];
    const float* dl = (const float*)d_in[2];
    const float* bl = (const float*)d_in[3];
    const float* et = (const float*)d_in[4];
    const float* pw = (const float*)d_in[5];
    const float* pb = (const float*)d_in[6];
    float* out = (float*)d_out;

    // workspace layout (16B aligned):
    //   z  bf16 [B,N,2C]           : 67,108,864 B
    //   P  f32  [2,B,64,H,C]       :  8,388,608 B
    //   Wb bf16 [512,1024]         :  1,048,576 B
    __hip_bfloat16* zb = (__hip_bfloat16*)d_ws;
    float*          P  = (float*)((char*)d_ws + 67108864);
    __hip_bfloat16* Wb = (__hip_bfloat16*)((char*)d_ws + 75497472);

    hipLaunchKernelGGL(k_cvtw,     dim3(2048),   dim3(256), 0, stream, pw, Wb);
    hipLaunchKernelGGL(k_partials, dim3(2048),   dim3(256), 0, stream, x, al, dl, bl, P);
    hipLaunchKernelGGL(k_scan,     dim3(128),    dim3(256), 0, stream, P);
    hipLaunchKernelGGL(k_apply,    dim3(2048),   dim3(256), 0, stream, x, al, dl, bl, et, P, zb);
    hipLaunchKernelGGL(k_gemm,     dim3(256, 4), dim3(256), 0, stream,
                       (const ushort_t*)zb, (const ushort_t*)Wb, pb, out);
}

// Round 2
// 340.070 us; speedup vs baseline: 1.0010x; 1.0010x over previous
//
#include <hip/hip_runtime.h>
#include <hip/hip_bf16.h>

#define B_ 8
#define N_ 4096
#define C_ 512
#define H_ 4
#define EPS_ 1e-4f
#define E60P 1.14200739e26f   // expf(60)
#define E60M 8.7565108e-27f   // expf(-60)

typedef __attribute__((ext_vector_type(8))) short short8;
typedef __attribute__((ext_vector_type(4))) float floatx4;
typedef unsigned short ushort_t;

__device__ __forceinline__ float sigmoidf_(float v) {
    return 1.0f / (1.0f + expf(-v));
}

// ---------------------------------------------------------------------------
// K1: per-subchunk (64 steps) partial sums  T[h] = sum A*x[t]*ep[t]
// grid: 2048 blocks; bid bits: dir(1) | chunk(4) | ct(3) | b(3)
// dir is the FASTEST bit and bwd chunk is mirrored (15-ch) so paired blocks
// read the same x rows -> L2/L3 reuse, HBM fetch of x ~halved.
// ---------------------------------------------------------------------------
__global__ __launch_bounds__(256) void k_partials(
    const float* __restrict__ x, const float* __restrict__ al,
    const float* __restrict__ dl, const float* __restrict__ bl,
    float* __restrict__ P)
{
    int bid   = blockIdx.x;
    int dir   = bid & 1;
    int craw  = (bid >> 1) & 15;
    int ct    = (bid >> 5) & 7;
    int b     = bid >> 8;
    int chunk = dir ? (15 - craw) : craw;
    int lane  = threadIdx.x & 63;
    int wave  = threadIdx.x >> 6;
    int c     = ct * 64 + lane;
    int sub   = chunk * 4 + wave;   // 0..63
    int t0    = sub * 64;

    float aa[4], dd[4], bb[4];
    { float4 v = ((const float4*)al)[c]; aa[0]=v.x; aa[1]=v.y; aa[2]=v.z; aa[3]=v.w; }
    { float4 v = ((const float4*)dl)[c]; dd[0]=v.x; dd[1]=v.y; dd[2]=v.z; dd[3]=v.w; }
    { float4 v = ((const float4*)bl)[c]; bb[0]=v.x; bb[1]=v.y; bb[2]=v.z; bb[3]=v.w; }

    float A[H_], ri[H_], ep[H_], T[H_];
    #pragma unroll
    for (int h = 0; h < H_; ++h) {
        float alpha = sigmoidf_(aa[h]);
        float delta = sigmoidf_(dd[h]);
        float beta  = sigmoidf_(bb[h]);
        A[h] = alpha * beta;
        float r = fminf(fmaxf(1.0f - alpha * delta, EPS_), 1.0f - EPS_);
        float L = logf(r);
        ri[h] = 1.0f / r;
        ep[h] = expf(fminf(-L * (float)t0, 60.0f));
        T[h]  = 0.0f;
    }

    const float* xb = x + (b * N_) * C_ + c;
    int nbase = dir ? (N_ - 1 - t0) : t0;
    int nstep = dir ? -1 : 1;

    #pragma unroll 8
    for (int i = 0; i < 64; ++i) {
        float xv = xb[(nbase + i * nstep) * C_];
        #pragma unroll
        for (int h = 0; h < H_; ++h) {
            float ax = A[h] * xv;
            T[h]  = fmaf(ax, ep[h], T[h]);
            ep[h] = fminf(ep[h] * ri[h], E60P);
        }
    }

    float* pp = P + ((dir * 8 + b) * 64 + sub) * (H_ * C_) + c;
    #pragma unroll
    for (int h = 0; h < H_; ++h) pp[h * C_] = T[h];
}

// ---------------------------------------------------------------------------
// K2: in-place exclusive scan over the 64 subchunks, per (dir,b,c,h)
// ---------------------------------------------------------------------------
__global__ __launch_bounds__(256) void k_scan(float* __restrict__ P)
{
    int bid = blockIdx.x;
    int ct  = bid & 7;
    int b   = (bid >> 3) & 7;
    int dir = bid >> 6;
    int cl  = threadIdx.x & 63;
    int h   = threadIdx.x >> 6;
    int c   = ct * 64 + cl;

    float run = 0.0f;
    float* base = P + ((dir * 8 + b) * 64) * (H_ * C_) + h * C_ + c;
    for (int s = 0; s < 64; ++s) {
        float v = base[s * (H_ * C_)];
        base[s * (H_ * C_)] = run;
        run += v;
    }
}

// ---------------------------------------------------------------------------
// K3: re-scan with carry, produce z[b,n,dir*C+c] (bf16). Same pairing as K1.
// ---------------------------------------------------------------------------
__global__ __launch_bounds__(256) void k_apply(
    const float* __restrict__ x, const float* __restrict__ al,
    const float* __restrict__ dl, const float* __restrict__ bl,
    const float* __restrict__ eta, const float* __restrict__ P,
    __hip_bfloat16* __restrict__ z)
{
    int bid   = blockIdx.x;
    int dir   = bid & 1;
    int craw  = (bid >> 1) & 15;
    int ct    = (bid >> 5) & 7;
    int b     = bid >> 8;
    int chunk = dir ? (15 - craw) : craw;
    int lane  = threadIdx.x & 63;
    int wave  = threadIdx.x >> 6;
    int c     = ct * 64 + lane;
    int sub   = chunk * 4 + wave;
    int t0    = sub * 64;

    float aa[4], dd[4], bb[4], ee[4];
    { float4 v = ((const float4*)al )[c]; aa[0]=v.x; aa[1]=v.y; aa[2]=v.z; aa[3]=v.w; }
    { float4 v = ((const float4*)dl )[c]; dd[0]=v.x; dd[1]=v.y; dd[2]=v.z; dd[3]=v.w; }
    { float4 v = ((const float4*)bl )[c]; bb[0]=v.x; bb[1]=v.y; bb[2]=v.z; bb[3]=v.w; }
    { float4 v = ((const float4*)eta)[c]; ee[0]=v.x; ee[1]=v.y; ee[2]=v.z; ee[3]=v.w; }

    const float* cp = P + ((dir * 8 + b) * 64 + sub) * (H_ * C_) + c;

    float A[H_], rr[H_], ri[H_], ep[H_], em[H_], S[H_];
    #pragma unroll
    for (int h = 0; h < H_; ++h) {
        float alpha = sigmoidf_(aa[h]);
        float delta = sigmoidf_(dd[h]);
        float beta  = sigmoidf_(bb[h]);
        A[h] = alpha * beta;
        float r = fminf(fmaxf(1.0f - alpha * delta, EPS_), 1.0f - EPS_);
        float L = logf(r);
        rr[h] = r;
        ri[h] = 1.0f / r;
        ep[h] = expf(fminf(-L * (float)t0, 60.0f));
        em[h] = expf(fmaxf( L * (float)t0, -60.0f));
        S[h]  = cp[h * C_];    // carry-in (exclusive prefix)
    }

    const float* xb = x + (b * N_) * C_ + c;
    __hip_bfloat16* zb = z + (b * N_) * (2 * C_) + dir * C_ + c;
    int nbase = dir ? (N_ - 1 - t0) : t0;
    int nstep = dir ? -1 : 1;

    #pragma unroll 4
    for (int i = 0; i < 64; ++i) {
        int n = nbase + i * nstep;
        float xv = xb[n * C_];
        float y = 0.0f;
        #pragma unroll
        for (int h = 0; h < H_; ++h) {
            float ax = A[h] * xv;
            S[h]  = fmaf(ax, ep[h], S[h]);
            ep[h] = fminf(ep[h] * ri[h], E60P);
            y     = fmaf(ee[h], em[h] * S[h], y);
            em[h] = fmaxf(em[h] * rr[h], E60M);
        }
        zb[n * (2 * C_)] = __float2bfloat16(y);
    }
}

// ---------------------------------------------------------------------------
__global__ __launch_bounds__(256) void k_cvtw(const float* __restrict__ w,
                                              __hip_bfloat16* __restrict__ wb)
{
    int i = blockIdx.x * 256 + threadIdx.x;   // 524288 total
    wb[i] = __float2bfloat16(w[i]);
}

// ---------------------------------------------------------------------------
// K4: GEMM  out[M=32768, 512] = Z[M,1024] * W[512,1024]^T + bias
// bf16 MFMA 16x16x32, BM=BN=128, BK=64. XOR-swizzled LDS (conflict-free),
// grid (n,m) so n-tiles of one m-tile co-resident, LDS-staged coalesced
// epilogue.
// ---------------------------------------------------------------------------
#define BM 128
#define BN 128
#define BK 64

__global__ __launch_bounds__(256) void k_gemm(
    const ushort_t* __restrict__ Z, const ushort_t* __restrict__ W,
    const float* __restrict__ bias, float* __restrict__ out)
{
    __shared__ __align__(16) ushort_t smem[2 * BM * BK];  // 32 KiB
    ushort_t* sA = smem;
    ushort_t* sB = smem + BM * BK;

    int tid  = threadIdx.x;
    int n0   = blockIdx.x * BN;
    int m0   = blockIdx.y * BM;
    int lane = tid & 63, wave = tid >> 6;
    int wm   = wave & 1, wn = wave >> 1;
    int fr   = lane & 15, quad = lane >> 4;

    floatx4 acc[4][4];
    #pragma unroll
    for (int mf = 0; mf < 4; ++mf)
        #pragma unroll
        for (int nf = 0; nf < 4; ++nf)
            acc[mf][nf] = (floatx4){0.f, 0.f, 0.f, 0.f};

    for (int k0 = 0; k0 < 1024; k0 += BK) {
        uint4 va[4], vb[4];
        #pragma unroll
        for (int j = 0; j < 4; ++j) {
            int q   = tid + j * 256;
            int row = q >> 3, kg = q & 7;
            va[j] = *(const uint4*)(Z + (m0 + row) * 1024 + k0 + kg * 8);
            vb[j] = *(const uint4*)(W + (n0 + row) * 1024 + k0 + kg * 8);
        }
        __syncthreads();
        #pragma unroll
        for (int j = 0; j < 4; ++j) {
            int q   = tid + j * 256;
            int row = q >> 3, kg = q & 7;
            int sw  = (kg ^ (row & 7)) * 8;          // XOR swizzle
            *(uint4*)&sA[row * BK + sw] = va[j];
            *(uint4*)&sB[row * BK + sw] = vb[j];
        }
        __syncthreads();

        short8 af[2][4], bf[2][4];
        #pragma unroll
        for (int ks = 0; ks < 2; ++ks)
            #pragma unroll
            for (int f = 0; f < 4; ++f) {
                int ra = wm * 64 + f * 16 + fr;
                int rb = wn * 64 + f * 16 + fr;
                int kc = ks * 4 + quad;
                af[ks][f] = *(const short8*)&sA[ra * BK + ((kc ^ (ra & 7)) * 8)];
                bf[ks][f] = *(const short8*)&sB[rb * BK + ((kc ^ (rb & 7)) * 8)];
            }

        #pragma unroll
        for (int ks = 0; ks < 2; ++ks)
            #pragma unroll
            for (int mf = 0; mf < 4; ++mf)
                #pragma unroll
                for (int nf = 0; nf < 4; ++nf)
                    acc[mf][nf] = __builtin_amdgcn_mfma_f32_16x16x32_bf16(
                        af[ks][mf], bf[ks][nf], acc[mf][nf], 0, 0, 0);
    }

    // ---- LDS-staged epilogue: 4 chunks of 32 rows, fully coalesced writes
    float* stg = (float*)smem;           // 32x132 fp32 = 16896 B <= 32 KiB
    int rrow = tid >> 3;                 // 0..31
    int seg  = tid & 7;                  // 0..7
    int gcol = n0 + seg * 16;

    __syncthreads();
    #pragma unroll
    for (int ch = 0; ch < 4; ++ch) {
        if ((wave & 1) == (ch >> 1)) {
            int ml = (ch & 1) * 2;
            #pragma unroll
            for (int mi = 0; mi < 2; ++mi) {
                #pragma unroll
                for (int nf = 0; nf < 4; ++nf) {
                    int col = wn * 64 + nf * 16 + fr;
                    #pragma unroll
                    for (int rg = 0; rg < 4; ++rg) {
                        int row = mi * 16 + quad * 4 + rg;
                        stg[row * 132 + col] = acc[ml + mi][nf][rg];
                    }
                }
            }
        }
        __syncthreads();
        {
            int gm = m0 + ch * 32 + rrow;
            const float* s = &stg[rrow * 132 + seg * 16];
            #pragma unroll
            for (int k = 0; k < 4; ++k) {
                float4 v = *(const float4*)&s[k * 4];
                float4 bv = *(const float4*)&bias[gcol + k * 4];
                v.x += bv.x; v.y += bv.y; v.z += bv.z; v.w += bv.w;
                *(float4*)&out[gm * 512 + gcol + k * 4] = v;
            }
        }
        __syncthreads();
    }
}

// ---------------------------------------------------------------------------
extern "C" void kernel_launch(void* const* d_in, const int* in_sizes, int n_in,
                              void* d_out, int out_size, void* d_ws, size_t ws_size,
                              hipStream_t stream)
{
    const float* x  = (const float*)d_in[0];
    const float* al = (const float*)d_in[1];
    const float* dl = (const float*)d_in[2];
    const float* bl = (const float*)d_in[3];
    const float* et = (const float*)d_in[4];
    const float* pw = (const float*)d_in[5];
    const float* pb = (const float*)d_in[6];
    float* out = (float*)d_out;

    // workspace layout (16B aligned):
    //   z  bf16 [B,N,2C]           : 67,108,864 B
    //   P  f32  [2,B,64,H,C]       :  8,388,608 B
    //   Wb bf16 [512,1024]         :  1,048,576 B
    __hip_bfloat16* zb = (__hip_bfloat16*)d_ws;
    float*          P  = (float*)((char*)d_ws + 67108864);
    __hip_bfloat16* Wb = (__hip_bfloat16*)((char*)d_ws + 75497472);

    hipLaunchKernelGGL(k_cvtw,     dim3(2048),   dim3(256), 0, stream, pw, Wb);
    hipLaunchKernelGGL(k_partials, dim3(2048),   dim3(256), 0, stream, x, al, dl, bl, P);
    hipLaunchKernelGGL(k_scan,     dim3(128),    dim3(256), 0, stream, P);
    hipLaunchKernelGGL(k_apply,    dim3(2048),   dim3(256), 0, stream, x, al, dl, bl, et, P, zb);
    hipLaunchKernelGGL(k_gemm,     dim3(4, 256), dim3(256), 0, stream,
                       (const ushort_t*)zb, (const ushort_t*)Wb, pb, out);
}

// Round 3
// 255.363 us; speedup vs baseline: 1.3331x; 1.3317x over previous
//
#include <hip/hip_runtime.h>
#include <hip/hip_bf16.h>

#define B_ 8
#define N_ 4096
#define C_ 512
#define H_ 4
#define EPS_ 1e-4f
#define E60P 1.14200739e26f   // expf(60)
#define E60M 8.7565108e-27f   // expf(-60)

typedef __attribute__((ext_vector_type(8))) short short8;
typedef __attribute__((ext_vector_type(4))) float floatx4;
typedef unsigned short ushort_t;

__device__ __forceinline__ float sigmoidf_(float v) {
    return 1.0f / (1.0f + expf(-v));
}

__device__ __forceinline__ void load_lds16(const ushort_t* g, ushort_t* l) {
    __builtin_amdgcn_global_load_lds(
        (const __attribute__((address_space(1))) void*)g,
        (__attribute__((address_space(3))) void*)l,
        16, 0, 0);
}

// ---------------------------------------------------------------------------
// K1: fused-direction per-subchunk partial sums.
// grid: 1024 blocks = chunk(4b) | ct(3b) | b(3b); 256 thr.
// wave = sub-within-chunk; lane = channel. x rows staged in LDS once,
// fwd pass reads ascending, bwd pass reads descending (same rows!).
// ---------------------------------------------------------------------------
__global__ __launch_bounds__(256) void k_partials2(
    const float* __restrict__ x, const float* __restrict__ al,
    const float* __restrict__ dl, const float* __restrict__ bl,
    float* __restrict__ P)
{
    __shared__ float sx[4][4096];   // 64 KiB: per-wave 64 rows x 64 chans

    int bid   = blockIdx.x;
    int chunk = bid & 15;
    int ct    = (bid >> 4) & 7;
    int b     = bid >> 7;
    int lane  = threadIdx.x & 63;
    int wave  = threadIdx.x >> 6;
    int c     = ct * 64 + lane;
    int sub   = chunk * 4 + wave;     // fwd subchunk 0..63
    int t0f   = sub * 64;
    int t0b   = (63 - sub) * 64;      // bwd subchunk start (in reversed time)

    // stage this wave's 64 x-rows (channels c) into LDS
    const float* xb = x + ((size_t)b * N_ + t0f) * C_ + c;
    float* sxe = sx[wave];
    #pragma unroll 8
    for (int i = 0; i < 64; ++i)
        sxe[i * 64 + lane] = xb[(size_t)i * C_];

    float aa[4], dd[4], bb[4];
    { float4 v = ((const float4*)al)[c]; aa[0]=v.x; aa[1]=v.y; aa[2]=v.z; aa[3]=v.w; }
    { float4 v = ((const float4*)dl)[c]; dd[0]=v.x; dd[1]=v.y; dd[2]=v.z; dd[3]=v.w; }
    { float4 v = ((const float4*)bl)[c]; bb[0]=v.x; bb[1]=v.y; bb[2]=v.z; bb[3]=v.w; }

    float A[H_], ri[H_], Lh[H_];
    #pragma unroll
    for (int h = 0; h < H_; ++h) {
        float alpha = sigmoidf_(aa[h]);
        float delta = sigmoidf_(dd[h]);
        float beta  = sigmoidf_(bb[h]);
        A[h] = alpha * beta;
        float r = fminf(fmaxf(1.0f - alpha * delta, EPS_), 1.0f - EPS_);
        Lh[h] = logf(r);
        ri[h] = 1.0f / r;
    }

    // ---- forward pass
    float ep[H_], T[H_];
    #pragma unroll
    for (int h = 0; h < H_; ++h) {
        ep[h] = expf(fminf(-Lh[h] * (float)t0f, 60.0f));
        T[h]  = 0.0f;
    }
    #pragma unroll 8
    for (int i = 0; i < 64; ++i) {
        float xv = sxe[i * 64 + lane];
        #pragma unroll
        for (int h = 0; h < H_; ++h) {
            T[h]  = fmaf(A[h] * xv, ep[h], T[h]);
            ep[h] = fminf(ep[h] * ri[h], E60P);
        }
    }
    {
        float* pp = P + ((size_t)(0 * 8 + b) * 64 + sub) * (H_ * C_) + c;
        #pragma unroll
        for (int h = 0; h < H_; ++h) pp[h * C_] = T[h];
    }

    // ---- backward pass: t' = t0b + j, row i = 63 - j
    #pragma unroll
    for (int h = 0; h < H_; ++h) {
        ep[h] = expf(fminf(-Lh[h] * (float)t0b, 60.0f));
        T[h]  = 0.0f;
    }
    #pragma unroll 8
    for (int j = 0; j < 64; ++j) {
        float xv = sxe[(63 - j) * 64 + lane];
        #pragma unroll
        for (int h = 0; h < H_; ++h) {
            T[h]  = fmaf(A[h] * xv, ep[h], T[h]);
            ep[h] = fminf(ep[h] * ri[h], E60P);
        }
    }
    {
        float* pp = P + ((size_t)(8 + b) * 64 + (63 - sub)) * (H_ * C_) + c;
        #pragma unroll
        for (int h = 0; h < H_; ++h) pp[h * C_] = T[h];
    }
}

// ---------------------------------------------------------------------------
// K2: in-place exclusive scan over the 64 subchunks, per (dir,b,c,h)
// ---------------------------------------------------------------------------
__global__ __launch_bounds__(256) void k_scan(float* __restrict__ P)
{
    int bid = blockIdx.x;
    int ct  = bid & 7;
    int b   = (bid >> 3) & 7;
    int dir = bid >> 6;
    int cl  = threadIdx.x & 63;
    int h   = threadIdx.x >> 6;
    int c   = ct * 64 + cl;

    float run = 0.0f;
    float* base = P + ((size_t)(dir * 8 + b) * 64) * (H_ * C_) + h * C_ + c;
    for (int s = 0; s < 64; ++s) {
        float v = base[s * (H_ * C_)];
        base[s * (H_ * C_)] = run;
        run += v;
    }
}

// ---------------------------------------------------------------------------
// K3: fused-direction apply: z[b,n,dir*C+c] (bf16), x staged in LDS once.
// ---------------------------------------------------------------------------
__global__ __launch_bounds__(256) void k_apply2(
    const float* __restrict__ x, const float* __restrict__ al,
    const float* __restrict__ dl, const float* __restrict__ bl,
    const float* __restrict__ eta, const float* __restrict__ P,
    __hip_bfloat16* __restrict__ z)
{
    __shared__ float sx[4][4096];

    int bid   = blockIdx.x;
    int chunk = bid & 15;
    int ct    = (bid >> 4) & 7;
    int b     = bid >> 7;
    int lane  = threadIdx.x & 63;
    int wave  = threadIdx.x >> 6;
    int c     = ct * 64 + lane;
    int sub   = chunk * 4 + wave;
    int t0f   = sub * 64;
    int t0b   = (63 - sub) * 64;

    const float* xb = x + ((size_t)b * N_ + t0f) * C_ + c;
    float* sxe = sx[wave];
    #pragma unroll 8
    for (int i = 0; i < 64; ++i)
        sxe[i * 64 + lane] = xb[(size_t)i * C_];

    float aa[4], dd[4], bb[4], ee[4];
    { float4 v = ((const float4*)al )[c]; aa[0]=v.x; aa[1]=v.y; aa[2]=v.z; aa[3]=v.w; }
    { float4 v = ((const float4*)dl )[c]; dd[0]=v.x; dd[1]=v.y; dd[2]=v.z; dd[3]=v.w; }
    { float4 v = ((const float4*)bl )[c]; bb[0]=v.x; bb[1]=v.y; bb[2]=v.z; bb[3]=v.w; }
    { float4 v = ((const float4*)eta)[c]; ee[0]=v.x; ee[1]=v.y; ee[2]=v.z; ee[3]=v.w; }

    float A[H_], rr[H_], ri[H_], Lh[H_];
    #pragma unroll
    for (int h = 0; h < H_; ++h) {
        float alpha = sigmoidf_(aa[h]);
        float delta = sigmoidf_(dd[h]);
        float beta  = sigmoidf_(bb[h]);
        A[h] = alpha * beta;
        float r = fminf(fmaxf(1.0f - alpha * delta, EPS_), 1.0f - EPS_);
        Lh[h] = logf(r);
        rr[h] = r;
        ri[h] = 1.0f / r;
    }

    __hip_bfloat16* zrow = z + (size_t)b * N_ * (2 * C_) + c;

    // ---- forward
    {
        const float* cp = P + ((size_t)b * 64 + sub) * (H_ * C_) + c;
        float ep[H_], em[H_], S[H_];
        #pragma unroll
        for (int h = 0; h < H_; ++h) {
            ep[h] = expf(fminf(-Lh[h] * (float)t0f, 60.0f));
            em[h] = expf(fmaxf( Lh[h] * (float)t0f, -60.0f));
            S[h]  = cp[h * C_];
        }
        #pragma unroll 4
        for (int i = 0; i < 64; ++i) {
            int n = t0f + i;
            float xv = sxe[i * 64 + lane];
            float y = 0.0f;
            #pragma unroll
            for (int h = 0; h < H_; ++h) {
                S[h]  = fmaf(A[h] * xv, ep[h], S[h]);
                ep[h] = fminf(ep[h] * ri[h], E60P);
                y     = fmaf(ee[h], em[h] * S[h], y);
                em[h] = fmaxf(em[h] * rr[h], E60M);
            }
            zrow[(size_t)n * (2 * C_)] = __float2bfloat16(y);
        }
    }

    // ---- backward: t' = t0b + j ascending, output row n = t0f + 63 - j
    {
        const float* cp = P + ((size_t)(8 + b) * 64 + (63 - sub)) * (H_ * C_) + c;
        float ep[H_], em[H_], S[H_];
        #pragma unroll
        for (int h = 0; h < H_; ++h) {
            ep[h] = expf(fminf(-Lh[h] * (float)t0b, 60.0f));
            em[h] = expf(fmaxf( Lh[h] * (float)t0b, -60.0f));
            S[h]  = cp[h * C_];
        }
        #pragma unroll 4
        for (int j = 0; j < 64; ++j) {
            int n = t0f + 63 - j;
            float xv = sxe[(63 - j) * 64 + lane];
            float y = 0.0f;
            #pragma unroll
            for (int h = 0; h < H_; ++h) {
                S[h]  = fmaf(A[h] * xv, ep[h], S[h]);
                ep[h] = fminf(ep[h] * ri[h], E60P);
                y     = fmaf(ee[h], em[h] * S[h], y);
                em[h] = fmaxf(em[h] * rr[h], E60M);
            }
            zrow[(size_t)n * (2 * C_) + C_] = __float2bfloat16(y);
        }
    }
}

// ---------------------------------------------------------------------------
__global__ __launch_bounds__(256) void k_cvtw(const float* __restrict__ w,
                                              __hip_bfloat16* __restrict__ wb)
{
    int i = blockIdx.x * 256 + threadIdx.x;   // 524288 total
    wb[i] = __float2bfloat16(w[i]);
}

// ---------------------------------------------------------------------------
// K4: GEMM out[32768,512] = Z[32768,1024] @ W[512,1024]^T + bias
// m97-style: global_load_lds(16B) into fragment-packed LDS chunks
// (1 KiB = one 16x32 operand tile in exact lane order), ds_read_b128 at
// base + lane*16 (conflict-free), 16x16x32 bf16 MFMA, XCD-aware swizzle.
// ---------------------------------------------------------------------------
__global__ __launch_bounds__(256) void k_gemm(
    const ushort_t* __restrict__ Z, const ushort_t* __restrict__ W,
    const float* __restrict__ bias, float* __restrict__ out)
{
    __shared__ __align__(16) ushort_t smem[32 * 512];  // 32 chunks x 1 KiB

    int tid  = threadIdx.x;
    int lane = tid & 63, wave = tid >> 6;
    int wm   = wave & 1, wn = wave >> 1;
    int fr   = lane & 15, quad = lane >> 4;

    // XCD-aware swizzle: lin&7 = XCD; the 4 n-tiles of one m-tile are
    // consecutive on the same XCD -> Z tile L2-resident.
    int lin = blockIdx.x;
    int xcd = lin & 7, j = lin >> 3;
    int m0  = (xcd * 32 + (j >> 2)) * 128;
    int n0  = (j & 3) * 128;

    // staging: 32 chunks (16 A + 16 B), 8 per wave.
    // chunk cid: 0..15 A (mt=cid>>1, kt=cid&1); 16..31 B (nt=(cid-16)>>1).
    // lane l fetches row (tile + 16*mt + (l&15)), k-bytes [kt*64 + (l>>4)*16).
    const ushort_t* gsrc[8];
    ushort_t*       ldst[8];
    {
        const ushort_t* gA = Z + (size_t)(m0 + fr) * 1024 + quad * 8;
        const ushort_t* gB = W + (size_t)(n0 + fr) * 1024 + quad * 8;
        #pragma unroll
        for (int ch = 0; ch < 8; ++ch) {
            int cid = wave * 8 + ch;
            int t   = cid & 15;
            const ushort_t* base = (cid < 16) ? gA : gB;
            gsrc[ch] = base + (size_t)((t >> 1) * 16) * 1024 + (t & 1) * 32;
            ldst[ch] = smem + cid * 512;
        }
    }

    floatx4 acc[4][4];
    #pragma unroll
    for (int mf = 0; mf < 4; ++mf)
        #pragma unroll
        for (int nf = 0; nf < 4; ++nf)
            acc[mf][nf] = (floatx4){0.f, 0.f, 0.f, 0.f};

    for (int k0 = 0; k0 < 1024; k0 += 64) {
        #pragma unroll
        for (int ch = 0; ch < 8; ++ch)
            load_lds16(gsrc[ch] + k0, ldst[ch]);
        __syncthreads();

        short8 af[2][4], bf[2][4];
        #pragma unroll
        for (int ks = 0; ks < 2; ++ks)
            #pragma unroll
            for (int f = 0; f < 4; ++f) {
                af[ks][f] = *(const short8*)&smem[(((wm * 4 + f) * 2 + ks)) * 512 + lane * 8];
                bf[ks][f] = *(const short8*)&smem[(16 + (wn * 4 + f) * 2 + ks) * 512 + lane * 8];
            }

        #pragma unroll
        for (int ks = 0; ks < 2; ++ks)
            #pragma unroll
            for (int mf = 0; mf < 4; ++mf)
                #pragma unroll
                for (int nf = 0; nf < 4; ++nf)
                    acc[mf][nf] = __builtin_amdgcn_mfma_f32_16x16x32_bf16(
                        af[ks][mf], bf[ks][nf], acc[mf][nf], 0, 0, 0);
        __syncthreads();
    }

    // ---- LDS-staged epilogue: 4 chunks of 32 rows, coalesced 512 B rows
    float* stg = (float*)smem;           // 32x132 fp32 = 16896 B <= 32 KiB
    int rrow = tid >> 3;                 // 0..31
    int seg  = tid & 7;                  // 0..7
    int gcol = n0 + seg * 16;

    #pragma unroll
    for (int ch = 0; ch < 4; ++ch) {
        if ((wave & 1) == (ch >> 1)) {
            int ml = (ch & 1) * 2;
            #pragma unroll
            for (int mi = 0; mi < 2; ++mi) {
                #pragma unroll
                for (int nf = 0; nf < 4; ++nf) {
                    int col = wn * 64 + nf * 16 + fr;
                    #pragma unroll
                    for (int rg = 0; rg < 4; ++rg) {
                        int row = mi * 16 + quad * 4 + rg;
                        stg[row * 132 + col] = acc[ml + mi][nf][rg];
                    }
                }
            }
        }
        __syncthreads();
        {
            int gm = m0 + ch * 32 + rrow;
            const float* s = &stg[rrow * 132 + seg * 16];
            #pragma unroll
            for (int k = 0; k < 4; ++k) {
                float4 v = *(const float4*)&s[k * 4];
                float4 bv = *(const float4*)&bias[gcol + k * 4];
                v.x += bv.x; v.y += bv.y; v.z += bv.z; v.w += bv.w;
                *(float4*)&out[(size_t)gm * 512 + gcol + k * 4] = v;
            }
        }
        __syncthreads();
    }
}

// ---------------------------------------------------------------------------
extern "C" void kernel_launch(void* const* d_in, const int* in_sizes, int n_in,
                              void* d_out, int out_size, void* d_ws, size_t ws_size,
                              hipStream_t stream)
{
    const float* x  = (const float*)d_in[0];
    const float* al = (const float*)d_in[1];
    const float* dl = (const float*)d_in[2];
    const float* bl = (const float*)d_in[3];
    const float* et = (const float*)d_in[4];
    const float* pw = (const float*)d_in[5];
    const float* pb = (const float*)d_in[6];
    float* out = (float*)d_out;

    // workspace layout:
    //   z  bf16 [B,N,2C]   : 67,108,864 B
    //   P  f32  [2,B,64,H,C]:  8,388,608 B
    //   Wb bf16 [512,1024] :  1,048,576 B
    __hip_bfloat16* zb = (__hip_bfloat16*)d_ws;
    float*          P  = (float*)((char*)d_ws + 67108864);
    __hip_bfloat16* Wb = (__hip_bfloat16*)((char*)d_ws + 75497472);

    hipLaunchKernelGGL(k_cvtw,      dim3(2048), dim3(256), 0, stream, pw, Wb);
    hipLaunchKernelGGL(k_partials2, dim3(1024), dim3(256), 0, stream, x, al, dl, bl, P);
    hipLaunchKernelGGL(k_scan,      dim3(128),  dim3(256), 0, stream, P);
    hipLaunchKernelGGL(k_apply2,    dim3(1024), dim3(256), 0, stream, x, al, dl, bl, et, P, zb);
    hipLaunchKernelGGL(k_gemm,      dim3(1024), dim3(256), 0, stream,
                       (const ushort_t*)zb, (const ushort_t*)Wb, pb, out);
}

// Round 4
// 237.415 us; speedup vs baseline: 1.4339x; 1.0756x over previous
//
#include <hip/hip_runtime.h>
#include <hip/hip_bf16.h>

#define B_ 8
#define N_ 4096
#define C_ 512
#define H_ 4
#define EPS_ 1e-4f
#define E60P 1.14200739e26f   // expf(60)
#define E60M 8.7565108e-27f   // expf(-60)

typedef __attribute__((ext_vector_type(8))) short short8;
typedef __attribute__((ext_vector_type(4))) float floatx4;
typedef unsigned short ushort_t;

__device__ __forceinline__ float sigmoidf_(float v) {
    return 1.0f / (1.0f + expf(-v));
}

// Fragment-packed layout for the GEMM operands (both Z and W):
//   chunk(tile t, half w, k0, ks, f) = 512 bf16 (1 KiB), element lane*8+kb
//   holds  Op[row = t*128 + w*64 + f*16 + (lane&15)]
//            [k  = k0*64 + ks*32 + (lane>>4)*8 + kb]
// i.e. exactly one 16x32 MFMA operand tile in lane order. A wave's K-stream
// for fixed (t,w) is contiguous 128 KiB.
__device__ __forceinline__ int pk_off(int t, int w, int k0, int ks, int f,
                                      int lane8, int kb) {
    return ((((t * 2 + w) * 16 + k0) * 2 + ks) * 4 + f) * 512 + lane8 * 8 + kb;
}

// ---------------------------------------------------------------------------
// K1: fused-direction per-subchunk partial sums, direct global reads.
// grid: 1024 = chunk(4b)|ct(3b)|b(3b); wave=sub-in-chunk, lane=channel.
// bwd pass re-reads the same 16 KB slice -> L1/L2 hit.
// ---------------------------------------------------------------------------
__global__ __launch_bounds__(256) void k_partials3(
    const float* __restrict__ x, const float* __restrict__ al,
    const float* __restrict__ dl, const float* __restrict__ bl,
    float* __restrict__ P)
{
    int bid   = blockIdx.x;
    int chunk = bid & 15;
    int ct    = (bid >> 4) & 7;
    int b     = bid >> 7;
    int lane  = threadIdx.x & 63;
    int wave  = threadIdx.x >> 6;
    int c     = ct * 64 + lane;
    int sub   = chunk * 4 + wave;     // fwd subchunk 0..63
    int t0f   = sub * 64;
    int t0b   = (63 - sub) * 64;      // bwd subchunk start (reversed time)

    float aa[4], dd[4], bb[4];
    { float4 v = ((const float4*)al)[c]; aa[0]=v.x; aa[1]=v.y; aa[2]=v.z; aa[3]=v.w; }
    { float4 v = ((const float4*)dl)[c]; dd[0]=v.x; dd[1]=v.y; dd[2]=v.z; dd[3]=v.w; }
    { float4 v = ((const float4*)bl)[c]; bb[0]=v.x; bb[1]=v.y; bb[2]=v.z; bb[3]=v.w; }

    float A[H_], ri[H_], Lh[H_];
    #pragma unroll
    for (int h = 0; h < H_; ++h) {
        float alpha = sigmoidf_(aa[h]);
        float delta = sigmoidf_(dd[h]);
        float beta  = sigmoidf_(bb[h]);
        A[h] = alpha * beta;
        float r = fminf(fmaxf(1.0f - alpha * delta, EPS_), 1.0f - EPS_);
        Lh[h] = logf(r);
        ri[h] = 1.0f / r;
    }

    const float* xp = x + ((size_t)b * N_ + t0f) * C_ + c;

    // ---- forward pass
    float ep[H_], T[H_];
    #pragma unroll
    for (int h = 0; h < H_; ++h) {
        ep[h] = expf(fminf(-Lh[h] * (float)t0f, 60.0f));
        T[h]  = 0.0f;
    }
    #pragma unroll 8
    for (int i = 0; i < 64; ++i) {
        float xv = xp[(size_t)i * C_];
        #pragma unroll
        for (int h = 0; h < H_; ++h) {
            T[h]  = fmaf(A[h] * xv, ep[h], T[h]);
            ep[h] = fminf(ep[h] * ri[h], E60P);
        }
    }
    {
        float* pp = P + ((size_t)b * 64 + sub) * (H_ * C_) + c;
        #pragma unroll
        for (int h = 0; h < H_; ++h) pp[h * C_] = T[h];
    }

    // ---- backward pass: t' = t0b + j, reads row 63-j (cache hit)
    #pragma unroll
    for (int h = 0; h < H_; ++h) {
        ep[h] = expf(fminf(-Lh[h] * (float)t0b, 60.0f));
        T[h]  = 0.0f;
    }
    #pragma unroll 8
    for (int j = 0; j < 64; ++j) {
        float xv = xp[(size_t)(63 - j) * C_];
        #pragma unroll
        for (int h = 0; h < H_; ++h) {
            T[h]  = fmaf(A[h] * xv, ep[h], T[h]);
            ep[h] = fminf(ep[h] * ri[h], E60P);
        }
    }
    {
        float* pp = P + ((size_t)(8 + b) * 64 + (63 - sub)) * (H_ * C_) + c;
        #pragma unroll
        for (int h = 0; h < H_; ++h) pp[h * C_] = T[h];
    }
}

// ---------------------------------------------------------------------------
// K2: in-place exclusive scan over the 64 subchunks, per (dir,b,c,h)
// ---------------------------------------------------------------------------
__global__ __launch_bounds__(256) void k_scan(float* __restrict__ P)
{
    int bid = blockIdx.x;
    int ct  = bid & 7;
    int b   = (bid >> 3) & 7;
    int dir = bid >> 6;
    int cl  = threadIdx.x & 63;
    int h   = threadIdx.x >> 6;
    int c   = ct * 64 + cl;

    float run = 0.0f;
    float* base = P + ((size_t)(dir * 8 + b) * 64) * (H_ * C_) + h * C_ + c;
    for (int s = 0; s < 64; ++s) {
        float v = base[s * (H_ * C_)];
        base[s * (H_ * C_)] = run;
        run += v;
    }
}

// ---------------------------------------------------------------------------
// K3: fused-direction apply; writes z directly in fragment-packed order.
// ---------------------------------------------------------------------------
__global__ __launch_bounds__(256) void k_apply3(
    const float* __restrict__ x, const float* __restrict__ al,
    const float* __restrict__ dl, const float* __restrict__ bl,
    const float* __restrict__ eta, const float* __restrict__ P,
    ushort_t* __restrict__ Zp)
{
    int bid   = blockIdx.x;
    int chunk = bid & 15;
    int ct    = (bid >> 4) & 7;
    int b     = bid >> 7;
    int lane  = threadIdx.x & 63;
    int wave  = threadIdx.x >> 6;
    int c     = ct * 64 + lane;
    int sub   = chunk * 4 + wave;
    int t0f   = sub * 64;
    int t0b   = (63 - sub) * 64;

    // packed-store per-thread constants: k = dir*512 + c
    int ksv = lane >> 5, qv = (lane >> 3) & 3, kbv = lane & 7;
    int k0f = ct;          // fwd  k0
    int k0b = 8 + ct;      // bwd  k0

    float aa[4], dd[4], bb[4], ee[4];
    { float4 v = ((const float4*)al )[c]; aa[0]=v.x; aa[1]=v.y; aa[2]=v.z; aa[3]=v.w; }
    { float4 v = ((const float4*)dl )[c]; dd[0]=v.x; dd[1]=v.y; dd[2]=v.z; dd[3]=v.w; }
    { float4 v = ((const float4*)bl )[c]; bb[0]=v.x; bb[1]=v.y; bb[2]=v.z; bb[3]=v.w; }
    { float4 v = ((const float4*)eta)[c]; ee[0]=v.x; ee[1]=v.y; ee[2]=v.z; ee[3]=v.w; }

    float A[H_], rr[H_], ri[H_], Lh[H_];
    #pragma unroll
    for (int h = 0; h < H_; ++h) {
        float alpha = sigmoidf_(aa[h]);
        float delta = sigmoidf_(dd[h]);
        float beta  = sigmoidf_(bb[h]);
        A[h] = alpha * beta;
        float r = fminf(fmaxf(1.0f - alpha * delta, EPS_), 1.0f - EPS_);
        Lh[h] = logf(r);
        rr[h] = r;
        ri[h] = 1.0f / r;
    }

    const float* xp = x + ((size_t)b * N_ + t0f) * C_ + c;

    // ---- forward
    {
        const float* cp = P + ((size_t)b * 64 + sub) * (H_ * C_) + c;
        float ep[H_], em[H_], S[H_];
        #pragma unroll
        for (int h = 0; h < H_; ++h) {
            ep[h] = expf(fminf(-Lh[h] * (float)t0f, 60.0f));
            em[h] = expf(fmaxf( Lh[h] * (float)t0f, -60.0f));
            S[h]  = cp[h * C_];
        }
        #pragma unroll 4
        for (int i = 0; i < 64; ++i) {
            int n  = t0f + i;
            float xv = xp[(size_t)i * C_];
            float y = 0.0f;
            #pragma unroll
            for (int h = 0; h < H_; ++h) {
                S[h]  = fmaf(A[h] * xv, ep[h], S[h]);
                ep[h] = fminf(ep[h] * ri[h], E60P);
                y     = fmaf(ee[h], em[h] * S[h], y);
                em[h] = fmaxf(em[h] * rr[h], E60M);
            }
            int rm = n & 127, mt = b * 32 + (n >> 7);
            int off = pk_off(mt, rm >> 6, k0f, ksv, (rm >> 4) & 3,
                             qv * 16 + (rm & 15), kbv);
            __hip_bfloat16 yb = __float2bfloat16(y);
            Zp[off] = *(ushort_t*)&yb;
        }
    }

    // ---- backward: t' = t0b + j ascending, output row n = t0f + 63 - j
    {
        const float* cp = P + ((size_t)(8 + b) * 64 + (63 - sub)) * (H_ * C_) + c;
        float ep[H_], em[H_], S[H_];
        #pragma unroll
        for (int h = 0; h < H_; ++h) {
            ep[h] = expf(fminf(-Lh[h] * (float)t0b, 60.0f));
            em[h] = expf(fmaxf( Lh[h] * (float)t0b, -60.0f));
            S[h]  = cp[h * C_];
        }
        #pragma unroll 4
        for (int j = 0; j < 64; ++j) {
            int n  = t0f + 63 - j;
            float xv = xp[(size_t)(63 - j) * C_];
            float y = 0.0f;
            #pragma unroll
            for (int h = 0; h < H_; ++h) {
                S[h]  = fmaf(A[h] * xv, ep[h], S[h]);
                ep[h] = fminf(ep[h] * ri[h], E60P);
                y     = fmaf(ee[h], em[h] * S[h], y);
                em[h] = fmaxf(em[h] * rr[h], E60M);
            }
            int rm = n & 127, mt = b * 32 + (n >> 7);
            int off = pk_off(mt, rm >> 6, k0b, ksv, (rm >> 4) & 3,
                             qv * 16 + (rm & 15), kbv);
            __hip_bfloat16 yb = __float2bfloat16(y);
            Zp[off] = *(ushort_t*)&yb;
        }
    }
}

// ---------------------------------------------------------------------------
// cvt + permute proj_w fp32 -> fragment-packed bf16
// ---------------------------------------------------------------------------
__global__ __launch_bounds__(256) void k_cvtw2(const float* __restrict__ w,
                                               ushort_t* __restrict__ Wp)
{
    int i = blockIdx.x * 256 + threadIdx.x;   // 524288 total
    int n = i >> 10, k = i & 1023;
    int nt = n >> 7, rn = n & 127;
    int k0 = k >> 6, kk = k & 63;
    int off = pk_off(nt, rn >> 6, k0, kk >> 5, (rn >> 4) & 3,
                     ((kk >> 3) & 3) * 16 + (rn & 15), kk & 7);
    __hip_bfloat16 vb = __float2bfloat16(w[i]);
    Wp[off] = *(ushort_t*)&vb;
}

// ---------------------------------------------------------------------------
// K4: GEMM out[32768,512] = Z @ W^T + bias, operands fragment-packed.
// NO LDS staging, NO barriers in the K-loop: each wave streams its A/B
// fragments as contiguous 1 KiB global_load_dwordx4 (whole K-stream is one
// contiguous 128 KiB run) -> compiler pipelines with fine-grained vmcnt.
// ---------------------------------------------------------------------------
__global__ __launch_bounds__(256, 2) void k_gemm2(
    const ushort_t* __restrict__ Zp, const ushort_t* __restrict__ Wp,
    const float* __restrict__ bias, float* __restrict__ out)
{
    __shared__ __align__(16) float stg[32 * 132];   // epilogue staging only

    int tid  = threadIdx.x;
    int lane = tid & 63, wave = tid >> 6;
    int wm   = wave & 1, wn = wave >> 1;
    int fr   = lane & 15, quad = lane >> 4;

    int lin = blockIdx.x;
    int nt  = lin & 3, mt = lin >> 2;
    int m0  = mt * 128, n0 = nt * 128;

    const ushort_t* Ab = Zp + ((size_t)(mt * 2 + wm) * 16) * 4096 + lane * 8;
    const ushort_t* Bb = Wp + ((size_t)(nt * 2 + wn) * 16) * 4096 + lane * 8;

    floatx4 acc[4][4];
    #pragma unroll
    for (int mf = 0; mf < 4; ++mf)
        #pragma unroll
        for (int nf = 0; nf < 4; ++nf)
            acc[mf][nf] = (floatx4){0.f, 0.f, 0.f, 0.f};

    #pragma unroll
    for (int k0 = 0; k0 < 16; ++k0) {
        short8 af[2][4], bf[2][4];
        #pragma unroll
        for (int ks = 0; ks < 2; ++ks)
            #pragma unroll
            for (int f = 0; f < 4; ++f) {
                af[ks][f] = *(const short8*)(Ab + k0 * 4096 + (ks * 4 + f) * 512);
                bf[ks][f] = *(const short8*)(Bb + k0 * 4096 + (ks * 4 + f) * 512);
            }
        #pragma unroll
        for (int ks = 0; ks < 2; ++ks)
            #pragma unroll
            for (int mf = 0; mf < 4; ++mf)
                #pragma unroll
                for (int nf = 0; nf < 4; ++nf)
                    acc[mf][nf] = __builtin_amdgcn_mfma_f32_16x16x32_bf16(
                        af[ks][mf], bf[ks][nf], acc[mf][nf], 0, 0, 0);
    }

    // ---- LDS-staged epilogue: 4 chunks of 32 rows, coalesced 512 B rows
    int rrow = tid >> 3;                 // 0..31
    int seg  = tid & 7;                  // 0..7
    int gcol = n0 + seg * 16;

    #pragma unroll
    for (int ch = 0; ch < 4; ++ch) {
        if ((wave & 1) == (ch >> 1)) {
            int ml = (ch & 1) * 2;
            #pragma unroll
            for (int mi = 0; mi < 2; ++mi) {
                #pragma unroll
                for (int nf = 0; nf < 4; ++nf) {
                    int col = wn * 64 + nf * 16 + fr;
                    #pragma unroll
                    for (int rg = 0; rg < 4; ++rg) {
                        int row = mi * 16 + quad * 4 + rg;
                        stg[row * 132 + col] = acc[ml + mi][nf][rg];
                    }
                }
            }
        }
        __syncthreads();
        {
            int gm = m0 + ch * 32 + rrow;
            const float* s = &stg[rrow * 132 + seg * 16];
            #pragma unroll
            for (int k = 0; k < 4; ++k) {
                float4 v  = *(const float4*)&s[k * 4];
                float4 bv = *(const float4*)&bias[gcol + k * 4];
                v.x += bv.x; v.y += bv.y; v.z += bv.z; v.w += bv.w;
                *(float4*)&out[(size_t)gm * 512 + gcol + k * 4] = v;
            }
        }
        __syncthreads();
    }
}

// ---------------------------------------------------------------------------
extern "C" void kernel_launch(void* const* d_in, const int* in_sizes, int n_in,
                              void* d_out, int out_size, void* d_ws, size_t ws_size,
                              hipStream_t stream)
{
    const float* x  = (const float*)d_in[0];
    const float* al = (const float*)d_in[1];
    const float* dl = (const float*)d_in[2];
    const float* bl = (const float*)d_in[3];
    const float* et = (const float*)d_in[4];
    const float* pw = (const float*)d_in[5];
    const float* pb = (const float*)d_in[6];
    float* out = (float*)d_out;

    // workspace:
    //   Zp bf16 packed [32768,1024] : 67,108,864 B
    //   P  f32  [2,B,64,H,C]        :  8,388,608 B
    //   Wp bf16 packed [512,1024]   :  1,048,576 B
    ushort_t* Zp = (ushort_t*)d_ws;
    float*    P  = (float*)((char*)d_ws + 67108864);
    ushort_t* Wp = (ushort_t*)((char*)d_ws + 75497472);

    hipLaunchKernelGGL(k_cvtw2,     dim3(2048), dim3(256), 0, stream, pw, Wp);
    hipLaunchKernelGGL(k_partials3, dim3(1024), dim3(256), 0, stream, x, al, dl, bl, P);
    hipLaunchKernelGGL(k_scan,      dim3(128),  dim3(256), 0, stream, P);
    hipLaunchKernelGGL(k_apply3,    dim3(1024), dim3(256), 0, stream, x, al, dl, bl, et, P, Zp);
    hipLaunchKernelGGL(k_gemm2,     dim3(1024), dim3(256), 0, stream, Zp, Wp, pb, out);
}